// Round 22
// baseline (350.567 us; speedup 1.0000x reference)
//
#include <hip/hip_runtime.h>
#include <math.h>

// Problem constants
#define B_    256
#define N_    128
#define F_    133
#define H_    8
#define ND_   64     // NHID
#define HID_  300
#define FPD_  1489
#define FP2_  512
#define ALPHA_ 0.2f
#define NEG_  -9.0e15f

typedef __bf16 bf16x8 __attribute__((ext_vector_type(8)));
typedef __bf16 bf16x4 __attribute__((ext_vector_type(4)));
typedef float f32x4 __attribute__((ext_vector_type(4)));

__device__ __forceinline__ float wred_sum(float v) {
#pragma unroll
  for (int m = 32; m >= 1; m >>= 1) v += __shfl_xor(v, m, 64);
  return v;
}
__device__ __forceinline__ float wred_max(float v) {
#pragma unroll
  for (int m = 32; m >= 1; m >>= 1) v = fmaxf(v, __shfl_xor(v, m, 64));
  return v;
}
__device__ __forceinline__ float lrelu(float x) { return x > 0.f ? x : ALPHA_ * x; }
__device__ __forceinline__ float eluf(float x)  { return x > 0.f ? x : expf(x) - 1.f; }
// 16B load at 4B alignment (safe form)
__device__ __forceinline__ float4 ld4u(const float* p) {
  float4 v;
  __builtin_memcpy(&v, p, 16);
  return v;
}

// Transpose + split-bf16 a KxN fp32 matrix into [N][K] hi/lo bf16 planes.
__global__ void k_wsplit(const float* __restrict__ Wm, __bf16* __restrict__ th,
                         __bf16* __restrict__ tl, int K, int Ncol) {
  const int idx = blockIdx.x * 256 + threadIdx.x;
  if (idx >= K * Ncol) return;
  const int k = idx / Ncol, c = idx - k * Ncol;
  float v = Wm[idx];
  __bf16 hv = (__bf16)v;
  th[(size_t)c * K + k] = hv;
  tl[(size_t)c * K + k] = (__bf16)(v - (float)hv);
}

// adj rows -> 2x u64 bitmask per row (bit l = adj[row][l] > 0). Used by k5.
__global__ __launch_bounds__(256) void k_amask(
    const int* __restrict__ adj, unsigned long long* __restrict__ mask) {
  const int lane = threadIdx.x & 63;
  const int row = blockIdx.x * 4 + (threadIdx.x >> 6);
  const int* arow = adj + (size_t)row * N_;
  unsigned long long b0 = __ballot(arow[lane] > 0);
  unsigned long long b1 = __ballot(arow[64 + lane] > 0);
  if (lane == 0) {
    mask[(size_t)row * 2] = b0;
    mask[(size_t)row * 2 + 1] = b1;
  }
}

// K1 (MFMA): Wh[b,h,n,d] fp32 from atom @ W_heads (split-bf16 MFMA).
// Block = 128 rows x 1 head, 512 thr / 8 waves. s/d epilogue from acc regs.
__global__ __launch_bounds__(512) void k1_mfma(
    const float* __restrict__ A, const float* __restrict__ W,
    const float* __restrict__ ahp, float* __restrict__ Wh,
    float* __restrict__ sb, float* __restrict__ db) {
  __shared__ __align__(16) __bf16 wth[64 * 168];
  __shared__ __align__(16) __bf16 wtl[64 * 168];
  const int tid = threadIdx.x;
  const int lane = tid & 63;
  const int wv = tid >> 6;
  const int h = blockIdx.y;
  const int m0 = blockIdx.x * 128;

  {
    const float* Wg = W + (size_t)h * F_ * ND_;
    const int d = tid >> 3;
    const int kq = tid & 7;
    for (int k = kq; k < 168; k += 8) {
      float v = (k < F_) ? Wg[k * ND_ + d] : 0.f;
      __bf16 hv = (__bf16)v;
      wth[d * 168 + k] = hv;
      wtl[d * 168 + k] = (__bf16)(v - (float)hv);
    }
  }
  __syncthreads();

  const int mrow = m0 + wv * 16 + (lane & 15);
  const float* Ap = A + (size_t)mrow * F_;
  f32x4 acc[4];
#pragma unroll
  for (int t = 0; t < 4; ++t) acc[t] = f32x4{0.f, 0.f, 0.f, 0.f};

#pragma unroll
  for (int ks = 0; ks < 5; ++ks) {
    const int kb = ks * 32 + (lane >> 4) * 8;
    float av[8];
    if (ks < 4) {
      float4 a0 = ld4u(Ap + kb);
      float4 a1 = ld4u(Ap + kb + 4);
      av[0] = a0.x; av[1] = a0.y; av[2] = a0.z; av[3] = a0.w;
      av[4] = a1.x; av[5] = a1.y; av[6] = a1.z; av[7] = a1.w;
    } else {
#pragma unroll
      for (int j = 0; j < 8; ++j)
        av[j] = (kb + j < F_) ? Ap[kb + j] : 0.f;
    }
    bf16x8 ah8, al8;
#pragma unroll
    for (int j = 0; j < 8; ++j) {
      float v = av[j];
      __bf16 hv = (__bf16)v;
      ah8[j] = hv;
      al8[j] = (__bf16)(v - (float)hv);
    }
#pragma unroll
    for (int ct = 0; ct < 4; ++ct) {
      const int d = ct * 16 + (lane & 15);
      bf16x8 bh8 = *reinterpret_cast<const bf16x8*>(&wth[d * 168 + kb]);
      bf16x8 bl8 = *reinterpret_cast<const bf16x8*>(&wtl[d * 168 + kb]);
      acc[ct] = __builtin_amdgcn_mfma_f32_16x16x32_bf16(al8, bh8, acc[ct], 0, 0, 0);
      acc[ct] = __builtin_amdgcn_mfma_f32_16x16x32_bf16(ah8, bl8, acc[ct], 0, 0, 0);
      acc[ct] = __builtin_amdgcn_mfma_f32_16x16x32_bf16(ah8, bh8, acc[ct], 0, 0, 0);
    }
  }

  const size_t bh = (size_t)blockIdx.x * H_ + h;
  float* Whb = Wh + bh * N_ * ND_;
  const int n0 = wv * 16 + (lane >> 4) * 4;
#pragma unroll
  for (int ct = 0; ct < 4; ++ct) {
    const int d = ct * 16 + (lane & 15);
#pragma unroll
    for (int r = 0; r < 4; ++r)
      Whb[(size_t)(n0 + r) * ND_ + d] = acc[ct][r];
  }

  {
    float a1v[4], a2v[4];
#pragma unroll
    for (int ct = 0; ct < 4; ++ct) {
      a1v[ct] = ahp[h * 2 * ND_ + ct * 16 + (lane & 15)];
      a2v[ct] = ahp[h * 2 * ND_ + ND_ + ct * 16 + (lane & 15)];
    }
#pragma unroll
    for (int r = 0; r < 4; ++r) {
      float sv = 0.f, dv = 0.f;
#pragma unroll
      for (int ct = 0; ct < 4; ++ct) {
        sv = fmaf(acc[ct][r], a1v[ct], sv);
        dv = fmaf(acc[ct][r], a2v[ct], dv);
      }
#pragma unroll
      for (int m = 1; m <= 8; m <<= 1) {
        sv += __shfl_xor(sv, m, 64);
        dv += __shfl_xor(dv, m, 64);
      }
      if ((lane & 15) == 0) {
        sb[bh * N_ + n0 + r] = sv;
        db[bh * N_ + n0 + r] = dv;
      }
    }
  }
}

// K2: masked softmax + h = elu(attn @ Wh) via MFMA.
// Wh panel converted to split-bf16 ONCE per block into LDS (was 8x redundant
// per-wave conversion); staging read coalesced (lane = d). One barrier.
// ph/pl remain wave-private (no barrier needed for them).
__global__ __launch_bounds__(512) void k2_attn1(
    const float* __restrict__ Wh, const float* __restrict__ sb,
    const float* __restrict__ db, const int* __restrict__ adj,
    __bf16* __restrict__ hbh, __bf16* __restrict__ hbl) {
  __shared__ __align__(16) __bf16 ph[128 * 136];
  __shared__ __align__(16) __bf16 pl[128 * 136];
  __shared__ __align__(16) __bf16 wbh[64 * 136];  // [d][n] hi plane
  __shared__ __align__(16) __bf16 wbl[64 * 136];  // [d][n] lo plane
  const int tid = threadIdx.x;
  const int lane = tid & 63;
  const int w = tid >> 6;
  const int bh = blockIdx.x;
  const int b = bh >> 3, h = bh & 7;
  const int i0 = w * 16;

  // Phase 0: stage Wh panel (transposed, split) into LDS once per block.
  {
    const float* Whp = Wh + (size_t)bh * N_ * ND_;
    const int d = lane;
#pragma unroll
    for (int r = 0; r < 16; ++r) {
      const int n = i0 + r;
      float v = Whp[(size_t)n * ND_ + d];   // coalesced across lanes
      __bf16 hv = (__bf16)v;
      wbh[d * 136 + n] = hv;
      wbl[d * 136 + n] = (__bf16)(v - (float)hv);
    }
  }
  __syncthreads();

  // Phase 1: masked softmax rows i0..i0+15 -> ph/pl (wave-private).
  {
    const float dv0 = db[(size_t)bh * N_ + lane];
    const float dv1 = db[(size_t)bh * N_ + 64 + lane];
    int a0v[16], a1v[16];
#pragma unroll
    for (int r = 0; r < 16; ++r) {
      const int* arow = adj + ((size_t)b * N_ + i0 + r) * N_;
      a0v[r] = arow[lane];
      a1v[r] = arow[64 + lane];
    }
#pragma unroll
    for (int r = 0; r < 16; ++r) {
      const int i = i0 + r;
      const float sv = sb[(size_t)bh * N_ + i];
      float e0 = a0v[r] > 0 ? lrelu(sv + dv0) : NEG_;
      float e1 = a1v[r] > 0 ? lrelu(sv + dv1) : NEG_;
      float mx = wred_max(fmaxf(e0, e1));
      float x0 = expf(e0 - mx), x1 = expf(e1 - mx);
      float inv = 1.f / wred_sum(x0 + x1);
      float p0 = x0 * inv, p1 = x1 * inv;
      __bf16 h0 = (__bf16)p0, h1 = (__bf16)p1;
      ph[i * 136 + lane] = h0;
      ph[i * 136 + 64 + lane] = h1;
      pl[i * 136 + lane] = (__bf16)(p0 - (float)h0);
      pl[i * 136 + 64 + lane] = (__bf16)(p1 - (float)h1);
    }
  }

  // Phase 2: rows i0..i0+15 = p_strip(16x128) @ Wh(128x64), MFMA.
  // B fragments now pure ds_read_b128 from the shared converted panel.
  {
    const int arow = i0 + (lane & 15);
    f32x4 acc[4];
#pragma unroll
    for (int t = 0; t < 4; ++t) acc[t] = f32x4{0.f, 0.f, 0.f, 0.f};
#pragma unroll
    for (int ks = 0; ks < 4; ++ks) {
      const int kb = ks * 32 + (lane >> 4) * 8;
      bf16x8 ah8 = *reinterpret_cast<const bf16x8*>(&ph[arow * 136 + kb]);
      bf16x8 al8 = *reinterpret_cast<const bf16x8*>(&pl[arow * 136 + kb]);
#pragma unroll
      for (int ct = 0; ct < 4; ++ct) {
        const int d = ct * 16 + (lane & 15);
        bf16x8 bh8 = *reinterpret_cast<const bf16x8*>(&wbh[d * 136 + kb]);
        bf16x8 bl8 = *reinterpret_cast<const bf16x8*>(&wbl[d * 136 + kb]);
        acc[ct] = __builtin_amdgcn_mfma_f32_16x16x32_bf16(al8, bh8, acc[ct], 0, 0, 0);
        acc[ct] = __builtin_amdgcn_mfma_f32_16x16x32_bf16(ah8, bl8, acc[ct], 0, 0, 0);
        acc[ct] = __builtin_amdgcn_mfma_f32_16x16x32_bf16(ah8, bh8, acc[ct], 0, 0, 0);
      }
    }
    const int orow0 = i0 + (lane >> 4) * 4;
#pragma unroll
    for (int ct = 0; ct < 4; ++ct) {
      const int d = ct * 16 + (lane & 15);
#pragma unroll
      for (int r = 0; r < 4; ++r) {
        const int i = orow0 + r;
        float ev = eluf(acc[ct][r]);
        __bf16 hv = (__bf16)ev;
        const size_t idx = ((size_t)b * N_ + i) * (H_ * ND_) + h * ND_ + d;
        hbh[idx] = hv;
        hbl[idx] = (__bf16)(ev - (float)hv);
      }
    }
  }
}

// Double-buffered LDS GEMM on pre-split operands.
// IS512: Wh2 transposed split pair + s2/d2 per-half partials.
// else : Cf = elu(acc) fp32 + per-col-half LSE partials into s2p/d2p.
template <int K, bool IS512>
__global__ __launch_bounds__(256) void gemm_lds(
    const __bf16* __restrict__ Ah, const __bf16* __restrict__ Al,
    const __bf16* __restrict__ BTh, const __bf16* __restrict__ BTl,
    const float* __restrict__ ao,
    __bf16* __restrict__ CTh, __bf16* __restrict__ CTl,
    float* __restrict__ s2p, float* __restrict__ d2p,
    float* __restrict__ Cf) {
  constexpr int NK = K / 32;
  __shared__ __align__(16) __bf16 lb[2][2][160 * 40];  // [buf][plane][col*40+k]
  const int tid = threadIdx.x;
  const int lane = tid & 63;
  const int w = tid >> 6;
  const int ch = blockIdx.y;
  const int colg0 = ch * 160;
  const int m0 = blockIdx.x * 64 + w * 16;
  const int row = m0 + (lane & 15);
  const int b = blockIdx.x >> 1;           // 64-row block -> batch (row/128)
  const __bf16* Bh_ = BTh + (IS512 ? (size_t)0 : (size_t)b * HID_ * K);
  const __bf16* Bl_ = BTl + (IS512 ? (size_t)0 : (size_t)b * HID_ * K);

  f32x4 acc[10];
#pragma unroll
  for (int t = 0; t < 10; ++t) acc[t] = f32x4{0.f, 0.f, 0.f, 0.f};

  bf16x8 sreg[5];

#define STAGE_LOAD(KS)                                                        \
  _Pragma("unroll") for (int r = 0; r < 5; ++r) {                             \
    const int un = r * 256 + tid;                                             \
    const int pl_ = un / 640, v_ = un % 640;                                  \
    const int col_ = v_ >> 2, kq_ = v_ & 3;                                   \
    const int colg_ = colg0 + col_;                                           \
    bf16x8 val = bf16x8{0, 0, 0, 0, 0, 0, 0, 0};                              \
    if (colg_ < HID_)                                                         \
      val = *reinterpret_cast<const bf16x8*>(                                 \
          (pl_ ? Bl_ : Bh_) + (size_t)colg_ * K + (KS) * 32 + kq_ * 8);       \
    sreg[r] = val;                                                            \
  }

#define STAGE_WRITE(BUF)                                                      \
  _Pragma("unroll") for (int r = 0; r < 5; ++r) {                             \
    const int un = r * 256 + tid;                                             \
    const int pl_ = un / 640, v_ = un % 640;                                  \
    const int col_ = v_ >> 2, kq_ = v_ & 3;                                   \
    *reinterpret_cast<bf16x8*>(&lb[(BUF)][pl_][col_ * 40 + kq_ * 8]) =        \
        sreg[r];                                                              \
  }

  int cur = 0;
  STAGE_LOAD(0)
  STAGE_WRITE(0)
  __syncthreads();

  for (int ks = 0; ks < NK; ++ks) {
    if (ks + 1 < NK) STAGE_LOAD(ks + 1)
    const int kb = ks * 32 + (lane >> 4) * 8;
    bf16x8 ah8 = *reinterpret_cast<const bf16x8*>(Ah + (size_t)row * K + kb);
    bf16x8 al8 = *reinterpret_cast<const bf16x8*>(Al + (size_t)row * K + kb);
#pragma unroll
    for (int t = 0; t < 10; ++t) {
      const int off = (t * 16 + (lane & 15)) * 40 + (lane >> 4) * 8;
      bf16x8 bh8 = *reinterpret_cast<const bf16x8*>(&lb[cur][0][off]);
      bf16x8 bl8 = *reinterpret_cast<const bf16x8*>(&lb[cur][1][off]);
      acc[t] = __builtin_amdgcn_mfma_f32_16x16x32_bf16(al8, bh8, acc[t], 0, 0, 0);
      acc[t] = __builtin_amdgcn_mfma_f32_16x16x32_bf16(ah8, bl8, acc[t], 0, 0, 0);
      acc[t] = __builtin_amdgcn_mfma_f32_16x16x32_bf16(ah8, bh8, acc[t], 0, 0, 0);
    }
    if (ks + 1 < NK) {
      STAGE_WRITE(cur ^ 1)
      __syncthreads();
    }
    cur ^= 1;
  }
#undef STAGE_LOAD
#undef STAGE_WRITE

  const int orow = m0 + (lane >> 4) * 4;
  if (IS512) {
    const int kloc0 = orow & 127;
#pragma unroll
    for (int t = 0; t < 10; ++t) {
      const int colg = colg0 + t * 16 + (lane & 15);
      if (colg < HID_) {
        bf16x4 hv4, lv4;
#pragma unroll
        for (int r = 0; r < 4; ++r) {
          float v = acc[t][r];
          __bf16 hv = (__bf16)v;
          hv4[r] = hv;
          lv4[r] = (__bf16)(v - (float)hv);
        }
        const size_t off = ((size_t)b * HID_ + colg) * 128 + kloc0;
        *reinterpret_cast<bf16x4*>(CTh + off) = hv4;
        *reinterpret_cast<bf16x4*>(CTl + off) = lv4;
      }
    }
    float aov[10], aod[10];
#pragma unroll
    for (int t = 0; t < 10; ++t) {
      const int colg = colg0 + t * 16 + (lane & 15);
      const bool cv = colg < HID_;
      aov[t] = cv ? ao[colg] : 0.f;
      aod[t] = cv ? ao[HID_ + colg] : 0.f;
    }
#pragma unroll
    for (int r = 0; r < 4; ++r) {
      float sv = 0.f, dv = 0.f;
#pragma unroll
      for (int t = 0; t < 10; ++t) {
        sv = fmaf(acc[t][r], aov[t], sv);
        dv = fmaf(acc[t][r], aod[t], dv);
      }
#pragma unroll
      for (int m = 1; m <= 8; m <<= 1) {
        sv += __shfl_xor(sv, m, 64);
        dv += __shfl_xor(dv, m, 64);
      }
      if ((lane & 15) == 0) {
        s2p[(size_t)ch * 32768 + orow + r] = sv;
        d2p[(size_t)ch * 32768 + orow + r] = dv;
      }
    }
  } else {
    // Store elu + per-row-half LSE partials (acc reused to hold elu values).
    float rm[4] = {-1e30f, -1e30f, -1e30f, -1e30f};
#pragma unroll
    for (int t = 0; t < 10; ++t) {
      const int colg = colg0 + t * 16 + (lane & 15);
      const bool cv = colg < HID_;
#pragma unroll
      for (int r = 0; r < 4; ++r) {
        float ev = cv ? eluf(acc[t][r]) : -1e30f;
        if (cv) Cf[(size_t)(orow + r) * HID_ + colg] = ev;
        acc[t][r] = ev;
        rm[r] = fmaxf(rm[r], ev);
      }
    }
#pragma unroll
    for (int r = 0; r < 4; ++r) {
#pragma unroll
      for (int m = 1; m <= 8; m <<= 1)
        rm[r] = fmaxf(rm[r], __shfl_xor(rm[r], m, 64));
      float ssum = 0.f;
#pragma unroll
      for (int t = 0; t < 10; ++t) ssum += expf(acc[t][r] - rm[r]);
#pragma unroll
      for (int m = 1; m <= 8; m <<= 1) ssum += __shfl_xor(ssum, m, 64);
      if ((lane & 15) == 0) {
        s2p[(size_t)ch * 32768 + orow + r] = rm[r];   // m_half
        d2p[(size_t)ch * 32768 + orow + r] = ssum;    // sumexp_half
      }
    }
  }
}

// Merge per-half LSE partials -> mx, ls.
__global__ __launch_bounds__(256) void k7b(
    const float* __restrict__ msp, const float* __restrict__ ssp,
    float* __restrict__ mx, float* __restrict__ ls) {
  const int row = blockIdx.x * 256 + threadIdx.x;
  float m0 = msp[row], m1 = msp[32768 + row];
  float s0 = ssp[row], s1 = ssp[32768 + row];
  float m = fmaxf(m0, m1);
  float s = s0 * expf(m0 - m) + s1 * expf(m1 - m);
  mx[row] = m;
  ls[row] = logf(s);
}

// Split-K partial GEMM for small-M matmuls: grid (M/ROWS, KSPLIT).
template <int ROWS, int KSPLIT>
__global__ void gemm_skp(const float* __restrict__ A, const float* __restrict__ Bm,
                         float* __restrict__ P, int M, int K, int N) {
  const int c = threadIdx.x;
  const int r0 = blockIdx.x * ROWS;
  const int ks = blockIdx.y;
  if (c >= N) return;
  const int kchunk = (K + KSPLIT - 1) / KSPLIT;
  const int k0 = ks * kchunk;
  const int k1 = (k0 + kchunk < K) ? (k0 + kchunk) : K;
  float acc[ROWS];
#pragma unroll
  for (int r = 0; r < ROWS; ++r) acc[r] = 0.f;
  int k = k0;
  for (; k + 3 < k1; k += 4) {
    const float b0 = Bm[(size_t)(k + 0) * N + c];
    const float b1 = Bm[(size_t)(k + 1) * N + c];
    const float b2 = Bm[(size_t)(k + 2) * N + c];
    const float b3 = Bm[(size_t)(k + 3) * N + c];
#pragma unroll
    for (int r = 0; r < ROWS; ++r) {
      float4 a = ld4u(A + (size_t)(r0 + r) * K + k);
      acc[r] = fmaf(a.x, b0, acc[r]);
      acc[r] = fmaf(a.y, b1, acc[r]);
      acc[r] = fmaf(a.z, b2, acc[r]);
      acc[r] = fmaf(a.w, b3, acc[r]);
    }
  }
  for (; k < k1; ++k) {
    const float bv = Bm[(size_t)k * N + c];
#pragma unroll
    for (int r = 0; r < ROWS; ++r)
      acc[r] = fmaf(A[(size_t)(r0 + r) * K + k], bv, acc[r]);
  }
#pragma unroll
  for (int r = 0; r < ROWS; ++r)
    P[((size_t)ks * M + r0 + r) * N + c] = acc[r];
}

// Reduce split-K partials + bias + act. act: 0 none, 1 relu.
template <int KSPLIT>
__global__ void k_red(const float* __restrict__ P, const float* __restrict__ bias,
                      float* __restrict__ C, int M, int N, int ldc, int act) {
  const int idx = blockIdx.x * 256 + threadIdx.x;
  if (idx >= M * N) return;
  const int m = idx / N, c = idx - m * N;
  float v = 0.f;
#pragma unroll
  for (int p = 0; p < KSPLIT; ++p) v += P[(size_t)p * M * N + idx];
  if (bias) v += bias[c];
  if (act == 1) v = fmaxf(v, 0.f);
  C[(size_t)m * ldc + c] = v;
}

// K5: attn2 probabilities p2 (split-bf16 pair); mask-based; sums s2/d2 halves.
__global__ __launch_bounds__(256) void k5_p2(
    const float* __restrict__ s2p, const float* __restrict__ d2p,
    const unsigned long long* __restrict__ maskb, __bf16* __restrict__ p2h,
    __bf16* __restrict__ p2l) {
  const int lane = threadIdx.x & 63;
  const int row = blockIdx.x * 4 + (threadIdx.x >> 6);  // b*N+i
  const int b = row >> 7;
  float sv = s2p[row] + s2p[32768 + row];
  const float* d0 = d2p + (size_t)b * N_;
  const float* d1 = d2p + 32768 + (size_t)b * N_;
  const unsigned long long m0 = maskb[(size_t)row * 2];
  const unsigned long long m1 = maskb[(size_t)row * 2 + 1];
  float dv0 = d0[lane] + d1[lane];
  float dv1 = d0[64 + lane] + d1[64 + lane];
  float e0 = ((m0 >> lane) & 1ull) ? lrelu(sv + dv0) : NEG_;
  float e1 = ((m1 >> lane) & 1ull) ? lrelu(sv + dv1) : NEG_;
  float mx = wred_max(fmaxf(e0, e1));
  float x0 = expf(e0 - mx), x1 = expf(e1 - mx);
  float inv = 1.f / wred_sum(x0 + x1);
  float p0 = x0 * inv, p1 = x1 * inv;
  __bf16 h0 = (__bf16)p0, h1 = (__bf16)p1;
  p2h[(size_t)row * N_ + lane] = h0;
  p2l[(size_t)row * N_ + lane] = (__bf16)(p0 - (float)h0);
  p2h[(size_t)row * N_ + 64 + lane] = h1;
  p2l[(size_t)row * N_ + 64 + lane] = (__bf16)(p1 - (float)h1);
}

// K8: gat_out[b,c] = mean_i (ob[b,i,c] - mx - ls). grid 256, block 320.
__global__ void k8_mean(const float* __restrict__ ob, const float* __restrict__ mx,
                        const float* __restrict__ ls, float* __restrict__ gat) {
  const int c = threadIdx.x;
  const int b = blockIdx.x;
  if (c >= HID_) return;
  float acc = 0.f;
  for (int i = 0; i < N_; ++i) {
    int row = b * N_ + i;
    acc += ob[(size_t)row * HID_ + c] - mx[row] - ls[row];
  }
  gat[(size_t)b * HID_ + c] = acc * (1.f / N_);
}

// out[b] = sigmoid(y[b,:] @ ffn_w2 + b2). One wave per row.
__global__ __launch_bounds__(256) void k_final(
    const float* __restrict__ y, const float* __restrict__ w2,
    const float* __restrict__ b2, float* __restrict__ out) {
  const int lane = threadIdx.x & 63;
  const int b = blockIdx.x * 4 + (threadIdx.x >> 6);
  float acc = 0.f;
  for (int c = lane; c < HID_; c += 64)
    acc = fmaf(y[(size_t)b * HID_ + c], w2[c], acc);
  acc = wred_sum(acc);
  if (lane == 0) out[b] = 1.f / (1.f + expf(-(acc + b2[0])));
}

extern "C" void kernel_launch(void* const* d_in, const int* in_sizes, int n_in,
                              void* d_out, int out_size, void* d_ws, size_t ws_size,
                              hipStream_t stream) {
  const float* atom  = (const float*)d_in[0];
  const float* fp    = (const float*)d_in[1];
  const float* Whead = (const float*)d_in[2];
  const float* ah    = (const float*)d_in[3];
  const float* Wout  = (const float*)d_in[4];
  const float* aout  = (const float*)d_in[5];
  const float* fc1w  = (const float*)d_in[6];
  const float* fc1b  = (const float*)d_in[7];
  const float* fc2w  = (const float*)d_in[8];
  const float* fc2b  = (const float*)d_in[9];
  const float* fgw   = (const float*)d_in[10];
  const float* fgb   = (const float*)d_in[11];
  const float* ffw   = (const float*)d_in[12];
  const float* ffb   = (const float*)d_in[13];
  const float* w1    = (const float*)d_in[14];
  const float* b1    = (const float*)d_in[15];
  const float* w2    = (const float*)d_in[16];
  const float* b2    = (const float*)d_in[17];
  const int*   adj   = (const int*)d_in[18];
  float* out = (float*)d_out;

  float* ws = (float*)d_ws;
  // Aliased layout (peak ~138.6 MB):
  float* Wh     = ws;                      // 16,777,216 f [k1 w, k2 r]
  __bf16* Wh2Th = (__bf16*)ws;             // 9.83M u16  [gemm512 w, gemm128 r]
  __bf16* Wh2Tl = (__bf16*)(ws + 4915200);
  float* pbuf   = ws;                      // [FPN + head phases only]
  __bf16* p2h   = (__bf16*)(ws + 9830400); // 4.19M u16 each
  __bf16* p2l   = (__bf16*)(ws + 11927552);
  float* s2p    = ws + 14024704;           // [2][32768]; reused as LSE m_half
  float* d2p    = ws + 14090240;           // [2][32768]; reused as sumexp_half
  unsigned long long* maskb =
      (unsigned long long*)(ws + 14155776); // 512 KB, verified free gap
  float* sb     = ws + 16777216;
  float* db     = ws + 17039360;
  __bf16* hbh   = (__bf16*)(ws + 17301504); // 16.7M u16 each
  __bf16* hbl   = (__bf16*)(ws + 25690112);
  float* ob     = ws + 17301504;           // [gemm128 w; hb pair dead]
  float* mxb    = ws + 34078720 + 65536;
  float* lsb    = mxb + 32768;
  float* gat    = lsb + 32768;             //  76,800
  float* fpn1   = gat + 76800;             // 131,072
  float* fpn2   = fpn1 + 131072;           //  76,800
  float* xcat   = fpn2 + 76800;            // 153,600
  float* yb     = xcat + 153600;           //  76,800
  __bf16* WoutTh = (__bf16*)xcat;          // WoutT pair borrows xcat slot
  __bf16* WoutTl = (__bf16*)(xcat + 76800);//  (dead before head phase)

  // Precompute: Wout split pair; adj bitmask (k5 only).
  k_wsplit<<<600, 256, 0, stream>>>(Wout, WoutTh, WoutTl, FP2_, HID_);
  k_amask<<<8192, 256, 0, stream>>>(adj, maskb);

  // FPN branch (pbuf aliases Wh region; runs before k1)
  gemm_skp<4, 8><<<dim3(64, 8), 512, 0, stream>>>(fp, fc1w, pbuf, B_, FPD_, FP2_);
  k_red<8><<<512, 256, 0, stream>>>(pbuf, fc1b, fpn1, B_, FP2_, FP2_, 1);
  gemm_skp<4, 4><<<dim3(64, 4), 320, 0, stream>>>(fpn1, fc2w, pbuf, B_, FP2_, HID_);
  k_red<4><<<300, 256, 0, stream>>>(pbuf, fc2b, fpn2, B_, HID_, HID_, 0);

  // GAT stage 1
  k1_mfma<<<dim3(256, 8), 512, 0, stream>>>(atom, Whead, ah, Wh, sb, db);
  k2_attn1<<<2048, 512, 0, stream>>>(Wh, sb, db, adj, hbh, hbl);

  // Wh2 = hb @ Wout (+fused s2/d2 partials), output transposed split pair.
  gemm_lds<512, true><<<dim3(512, 2), 256, 0, stream>>>(
      hbh, hbl, WoutTh, WoutTl, aout, Wh2Th, Wh2Tl, s2p, d2p, nullptr);

  // GAT stage 2
  k5_p2<<<8192, 256, 0, stream>>>(s2p, d2p, maskb, p2h, p2l);
  // gemm128 writes ob + LSE partials into s2p/d2p (dead after k5).
  gemm_lds<128, false><<<dim3(512, 2), 256, 0, stream>>>(
      p2h, p2l, Wh2Th, Wh2Tl, nullptr, nullptr, nullptr, s2p, d2p, ob);
  k7b<<<128, 256, 0, stream>>>(s2p, d2p, mxb, lsb);
  k8_mean<<<256, 320, 0, stream>>>(ob, mxb, lsb, gat);

  // Head (low ws region dead -> pbuf reuse safe; xcat written after WoutT dead)
  gemm_skp<4, 4><<<dim3(64, 4), 320, 0, stream>>>(gat, fgw, pbuf, B_, HID_, HID_);
  k_red<4><<<300, 256, 0, stream>>>(pbuf, fgb, xcat, B_, HID_, 2 * HID_, 1);
  gemm_skp<4, 4><<<dim3(64, 4), 320, 0, stream>>>(fpn2, ffw, pbuf, B_, HID_, HID_);
  k_red<4><<<300, 256, 0, stream>>>(pbuf, ffb, xcat + 300, B_, HID_, 2 * HID_, 1);
  gemm_skp<4, 4><<<dim3(64, 4), 320, 0, stream>>>(xcat, w1, pbuf, B_, 2 * HID_, HID_);
  k_red<4><<<300, 256, 0, stream>>>(pbuf, b1, yb, B_, HID_, HID_, 1);
  k_final<<<64, 256, 0, stream>>>(yb, w2, b2, out);
}

// Round 23
// 321.880 us; speedup vs baseline: 1.0891x; 1.0891x over previous
//
#include <hip/hip_runtime.h>
#include <math.h>

// Problem constants
#define B_    256
#define N_    128
#define F_    133
#define H_    8
#define ND_   64     // NHID
#define HID_  300
#define FPD_  1489
#define FP2_  512
#define ALPHA_ 0.2f
#define NEG_  -9.0e15f

typedef __bf16 bf16x8 __attribute__((ext_vector_type(8)));
typedef __bf16 bf16x4 __attribute__((ext_vector_type(4)));
typedef float f32x4 __attribute__((ext_vector_type(4)));

__device__ __forceinline__ float wred_sum(float v) {
#pragma unroll
  for (int m = 32; m >= 1; m >>= 1) v += __shfl_xor(v, m, 64);
  return v;
}
__device__ __forceinline__ float wred_max(float v) {
#pragma unroll
  for (int m = 32; m >= 1; m >>= 1) v = fmaxf(v, __shfl_xor(v, m, 64));
  return v;
}
__device__ __forceinline__ float lrelu(float x) { return x > 0.f ? x : ALPHA_ * x; }
__device__ __forceinline__ float eluf(float x)  { return x > 0.f ? x : expf(x) - 1.f; }
// 16B load at 4B alignment (safe form)
__device__ __forceinline__ float4 ld4u(const float* p) {
  float4 v;
  __builtin_memcpy(&v, p, 16);
  return v;
}

// Transpose + split-bf16 a KxN fp32 matrix into [N][K] hi/lo bf16 planes.
__global__ void k_wsplit(const float* __restrict__ Wm, __bf16* __restrict__ th,
                         __bf16* __restrict__ tl, int K, int Ncol) {
  const int idx = blockIdx.x * 256 + threadIdx.x;
  if (idx >= K * Ncol) return;
  const int k = idx / Ncol, c = idx - k * Ncol;
  float v = Wm[idx];
  __bf16 hv = (__bf16)v;
  th[(size_t)c * K + k] = hv;
  tl[(size_t)c * K + k] = (__bf16)(v - (float)hv);
}

// adj rows -> 2x u64 bitmask per row (bit l = adj[row][l] > 0). Used by k5.
__global__ __launch_bounds__(256) void k_amask(
    const int* __restrict__ adj, unsigned long long* __restrict__ mask) {
  const int lane = threadIdx.x & 63;
  const int row = blockIdx.x * 4 + (threadIdx.x >> 6);
  const int* arow = adj + (size_t)row * N_;
  unsigned long long b0 = __ballot(arow[lane] > 0);
  unsigned long long b1 = __ballot(arow[64 + lane] > 0);
  if (lane == 0) {
    mask[(size_t)row * 2] = b0;
    mask[(size_t)row * 2 + 1] = b1;
  }
}

// K1 (MFMA): Wh[b,h,n,d] fp32 from atom @ W_heads (split-bf16 MFMA).
// Block = 128 rows x 1 head, 512 thr / 8 waves. s/d epilogue from acc regs.
__global__ __launch_bounds__(512) void k1_mfma(
    const float* __restrict__ A, const float* __restrict__ W,
    const float* __restrict__ ahp, float* __restrict__ Wh,
    float* __restrict__ sb, float* __restrict__ db) {
  __shared__ __align__(16) __bf16 wth[64 * 168];
  __shared__ __align__(16) __bf16 wtl[64 * 168];
  const int tid = threadIdx.x;
  const int lane = tid & 63;
  const int wv = tid >> 6;
  const int h = blockIdx.y;
  const int m0 = blockIdx.x * 128;

  {
    const float* Wg = W + (size_t)h * F_ * ND_;
    const int d = tid >> 3;
    const int kq = tid & 7;
    for (int k = kq; k < 168; k += 8) {
      float v = (k < F_) ? Wg[k * ND_ + d] : 0.f;
      __bf16 hv = (__bf16)v;
      wth[d * 168 + k] = hv;
      wtl[d * 168 + k] = (__bf16)(v - (float)hv);
    }
  }
  __syncthreads();

  const int mrow = m0 + wv * 16 + (lane & 15);
  const float* Ap = A + (size_t)mrow * F_;
  f32x4 acc[4];
#pragma unroll
  for (int t = 0; t < 4; ++t) acc[t] = f32x4{0.f, 0.f, 0.f, 0.f};

#pragma unroll
  for (int ks = 0; ks < 5; ++ks) {
    const int kb = ks * 32 + (lane >> 4) * 8;
    float av[8];
    if (ks < 4) {
      float4 a0 = ld4u(Ap + kb);
      float4 a1 = ld4u(Ap + kb + 4);
      av[0] = a0.x; av[1] = a0.y; av[2] = a0.z; av[3] = a0.w;
      av[4] = a1.x; av[5] = a1.y; av[6] = a1.z; av[7] = a1.w;
    } else {
#pragma unroll
      for (int j = 0; j < 8; ++j)
        av[j] = (kb + j < F_) ? Ap[kb + j] : 0.f;
    }
    bf16x8 ah8, al8;
#pragma unroll
    for (int j = 0; j < 8; ++j) {
      float v = av[j];
      __bf16 hv = (__bf16)v;
      ah8[j] = hv;
      al8[j] = (__bf16)(v - (float)hv);
    }
#pragma unroll
    for (int ct = 0; ct < 4; ++ct) {
      const int d = ct * 16 + (lane & 15);
      bf16x8 bh8 = *reinterpret_cast<const bf16x8*>(&wth[d * 168 + kb]);
      bf16x8 bl8 = *reinterpret_cast<const bf16x8*>(&wtl[d * 168 + kb]);
      acc[ct] = __builtin_amdgcn_mfma_f32_16x16x32_bf16(al8, bh8, acc[ct], 0, 0, 0);
      acc[ct] = __builtin_amdgcn_mfma_f32_16x16x32_bf16(ah8, bl8, acc[ct], 0, 0, 0);
      acc[ct] = __builtin_amdgcn_mfma_f32_16x16x32_bf16(ah8, bh8, acc[ct], 0, 0, 0);
    }
  }

  const size_t bh = (size_t)blockIdx.x * H_ + h;
  float* Whb = Wh + bh * N_ * ND_;
  const int n0 = wv * 16 + (lane >> 4) * 4;
#pragma unroll
  for (int ct = 0; ct < 4; ++ct) {
    const int d = ct * 16 + (lane & 15);
#pragma unroll
    for (int r = 0; r < 4; ++r)
      Whb[(size_t)(n0 + r) * ND_ + d] = acc[ct][r];
  }

  {
    float a1v[4], a2v[4];
#pragma unroll
    for (int ct = 0; ct < 4; ++ct) {
      a1v[ct] = ahp[h * 2 * ND_ + ct * 16 + (lane & 15)];
      a2v[ct] = ahp[h * 2 * ND_ + ND_ + ct * 16 + (lane & 15)];
    }
#pragma unroll
    for (int r = 0; r < 4; ++r) {
      float sv = 0.f, dv = 0.f;
#pragma unroll
      for (int ct = 0; ct < 4; ++ct) {
        sv = fmaf(acc[ct][r], a1v[ct], sv);
        dv = fmaf(acc[ct][r], a2v[ct], dv);
      }
#pragma unroll
      for (int m = 1; m <= 8; m <<= 1) {
        sv += __shfl_xor(sv, m, 64);
        dv += __shfl_xor(dv, m, 64);
      }
      if ((lane & 15) == 0) {
        sb[bh * N_ + n0 + r] = sv;
        db[bh * N_ + n0 + r] = dv;
      }
    }
  }
}

// K2 (round-17/21 form — empirical optimum): masked softmax + h =
// elu(attn @ Wh) via MFMA. Barrier-free; Wh fp32 B-operand with inline
// split (conversion VALU hides B-load latency at 3-block occupancy;
// measured faster than pre-split global AND pre-split LDS variants).
__global__ __launch_bounds__(512) void k2_attn1(
    const float* __restrict__ Wh, const float* __restrict__ sb,
    const float* __restrict__ db, const int* __restrict__ adj,
    __bf16* __restrict__ hbh, __bf16* __restrict__ hbl) {
  __shared__ __align__(16) __bf16 ph[128 * 136];
  __shared__ __align__(16) __bf16 pl[128 * 136];
  const int tid = threadIdx.x;
  const int lane = tid & 63;
  const int w = tid >> 6;
  const int bh = blockIdx.x;
  const int b = bh >> 3, h = bh & 7;
  const int i0 = w * 16;

  {
    const float dv0 = db[(size_t)bh * N_ + lane];
    const float dv1 = db[(size_t)bh * N_ + 64 + lane];
    int a0v[16], a1v[16];
#pragma unroll
    for (int r = 0; r < 16; ++r) {
      const int* arow = adj + ((size_t)b * N_ + i0 + r) * N_;
      a0v[r] = arow[lane];
      a1v[r] = arow[64 + lane];
    }
#pragma unroll
    for (int r = 0; r < 16; ++r) {
      const int i = i0 + r;
      const float sv = sb[(size_t)bh * N_ + i];
      float e0 = a0v[r] > 0 ? lrelu(sv + dv0) : NEG_;
      float e1 = a1v[r] > 0 ? lrelu(sv + dv1) : NEG_;
      float mx = wred_max(fmaxf(e0, e1));
      float x0 = expf(e0 - mx), x1 = expf(e1 - mx);
      float inv = 1.f / wred_sum(x0 + x1);
      float p0 = x0 * inv, p1 = x1 * inv;
      __bf16 h0 = (__bf16)p0, h1 = (__bf16)p1;
      ph[i * 136 + lane] = h0;
      ph[i * 136 + 64 + lane] = h1;
      pl[i * 136 + lane] = (__bf16)(p0 - (float)h0);
      pl[i * 136 + 64 + lane] = (__bf16)(p1 - (float)h1);
    }
  }
  // No __syncthreads: wave reads only rows it wrote.

  {
    const int arow = i0 + (lane & 15);
    const float* Whp = Wh + (size_t)bh * N_ * ND_;
    f32x4 acc[4];
#pragma unroll
    for (int t = 0; t < 4; ++t) acc[t] = f32x4{0.f, 0.f, 0.f, 0.f};
#pragma unroll
    for (int ks = 0; ks < 4; ++ks) {
      const int kb = ks * 32 + (lane >> 4) * 8;
      bf16x8 ah8 = *reinterpret_cast<const bf16x8*>(&ph[arow * 136 + kb]);
      bf16x8 al8 = *reinterpret_cast<const bf16x8*>(&pl[arow * 136 + kb]);
#pragma unroll
      for (int ct = 0; ct < 4; ++ct) {
        const int d = ct * 16 + (lane & 15);
        const float* Bc = Whp + (size_t)kb * ND_ + d;
        float bv[8];
#pragma unroll
        for (int i = 0; i < 8; ++i) bv[i] = Bc[(size_t)i * ND_];
        bf16x8 bh8, bl8;
#pragma unroll
        for (int j = 0; j < 8; ++j) {
          float v = bv[j];
          __bf16 hv = (__bf16)v;
          bh8[j] = hv;
          bl8[j] = (__bf16)(v - (float)hv);
        }
        acc[ct] = __builtin_amdgcn_mfma_f32_16x16x32_bf16(al8, bh8, acc[ct], 0, 0, 0);
        acc[ct] = __builtin_amdgcn_mfma_f32_16x16x32_bf16(ah8, bl8, acc[ct], 0, 0, 0);
        acc[ct] = __builtin_amdgcn_mfma_f32_16x16x32_bf16(ah8, bh8, acc[ct], 0, 0, 0);
      }
    }
    const int orow0 = i0 + (lane >> 4) * 4;
#pragma unroll
    for (int ct = 0; ct < 4; ++ct) {
      const int d = ct * 16 + (lane & 15);
#pragma unroll
      for (int r = 0; r < 4; ++r) {
        const int i = orow0 + r;
        float ev = eluf(acc[ct][r]);
        __bf16 hv = (__bf16)ev;
        const size_t idx = ((size_t)b * N_ + i) * (H_ * ND_) + h * ND_ + d;
        hbh[idx] = hv;
        hbl[idx] = (__bf16)(ev - (float)hv);
      }
    }
  }
}

// Double-buffered LDS GEMM on pre-split operands.
// IS512: Wh2 transposed split pair + s2/d2 per-half partials.
// else : Cf = elu(acc) fp32 + per-col-half LSE partials into s2p/d2p.
template <int K, bool IS512>
__global__ __launch_bounds__(256) void gemm_lds(
    const __bf16* __restrict__ Ah, const __bf16* __restrict__ Al,
    const __bf16* __restrict__ BTh, const __bf16* __restrict__ BTl,
    const float* __restrict__ ao,
    __bf16* __restrict__ CTh, __bf16* __restrict__ CTl,
    float* __restrict__ s2p, float* __restrict__ d2p,
    float* __restrict__ Cf) {
  constexpr int NK = K / 32;
  __shared__ __align__(16) __bf16 lb[2][2][160 * 40];  // [buf][plane][col*40+k]
  const int tid = threadIdx.x;
  const int lane = tid & 63;
  const int w = tid >> 6;
  const int ch = blockIdx.y;
  const int colg0 = ch * 160;
  const int m0 = blockIdx.x * 64 + w * 16;
  const int row = m0 + (lane & 15);
  const int b = blockIdx.x >> 1;           // 64-row block -> batch (row/128)
  const __bf16* Bh_ = BTh + (IS512 ? (size_t)0 : (size_t)b * HID_ * K);
  const __bf16* Bl_ = BTl + (IS512 ? (size_t)0 : (size_t)b * HID_ * K);

  f32x4 acc[10];
#pragma unroll
  for (int t = 0; t < 10; ++t) acc[t] = f32x4{0.f, 0.f, 0.f, 0.f};

  bf16x8 sreg[5];

#define STAGE_LOAD(KS)                                                        \
  _Pragma("unroll") for (int r = 0; r < 5; ++r) {                             \
    const int un = r * 256 + tid;                                             \
    const int pl_ = un / 640, v_ = un % 640;                                  \
    const int col_ = v_ >> 2, kq_ = v_ & 3;                                   \
    const int colg_ = colg0 + col_;                                           \
    bf16x8 val = bf16x8{0, 0, 0, 0, 0, 0, 0, 0};                              \
    if (colg_ < HID_)                                                         \
      val = *reinterpret_cast<const bf16x8*>(                                 \
          (pl_ ? Bl_ : Bh_) + (size_t)colg_ * K + (KS) * 32 + kq_ * 8);       \
    sreg[r] = val;                                                            \
  }

#define STAGE_WRITE(BUF)                                                      \
  _Pragma("unroll") for (int r = 0; r < 5; ++r) {                             \
    const int un = r * 256 + tid;                                             \
    const int pl_ = un / 640, v_ = un % 640;                                  \
    const int col_ = v_ >> 2, kq_ = v_ & 3;                                   \
    *reinterpret_cast<bf16x8*>(&lb[(BUF)][pl_][col_ * 40 + kq_ * 8]) =        \
        sreg[r];                                                              \
  }

  int cur = 0;
  STAGE_LOAD(0)
  STAGE_WRITE(0)
  __syncthreads();

  for (int ks = 0; ks < NK; ++ks) {
    if (ks + 1 < NK) STAGE_LOAD(ks + 1)
    const int kb = ks * 32 + (lane >> 4) * 8;
    bf16x8 ah8 = *reinterpret_cast<const bf16x8*>(Ah + (size_t)row * K + kb);
    bf16x8 al8 = *reinterpret_cast<const bf16x8*>(Al + (size_t)row * K + kb);
#pragma unroll
    for (int t = 0; t < 10; ++t) {
      const int off = (t * 16 + (lane & 15)) * 40 + (lane >> 4) * 8;
      bf16x8 bh8 = *reinterpret_cast<const bf16x8*>(&lb[cur][0][off]);
      bf16x8 bl8 = *reinterpret_cast<const bf16x8*>(&lb[cur][1][off]);
      acc[t] = __builtin_amdgcn_mfma_f32_16x16x32_bf16(al8, bh8, acc[t], 0, 0, 0);
      acc[t] = __builtin_amdgcn_mfma_f32_16x16x32_bf16(ah8, bl8, acc[t], 0, 0, 0);
      acc[t] = __builtin_amdgcn_mfma_f32_16x16x32_bf16(ah8, bh8, acc[t], 0, 0, 0);
    }
    if (ks + 1 < NK) {
      STAGE_WRITE(cur ^ 1)
      __syncthreads();
    }
    cur ^= 1;
  }
#undef STAGE_LOAD
#undef STAGE_WRITE

  const int orow = m0 + (lane >> 4) * 4;
  if (IS512) {
    const int kloc0 = orow & 127;
#pragma unroll
    for (int t = 0; t < 10; ++t) {
      const int colg = colg0 + t * 16 + (lane & 15);
      if (colg < HID_) {
        bf16x4 hv4, lv4;
#pragma unroll
        for (int r = 0; r < 4; ++r) {
          float v = acc[t][r];
          __bf16 hv = (__bf16)v;
          hv4[r] = hv;
          lv4[r] = (__bf16)(v - (float)hv);
        }
        const size_t off = ((size_t)b * HID_ + colg) * 128 + kloc0;
        *reinterpret_cast<bf16x4*>(CTh + off) = hv4;
        *reinterpret_cast<bf16x4*>(CTl + off) = lv4;
      }
    }
    float aov[10], aod[10];
#pragma unroll
    for (int t = 0; t < 10; ++t) {
      const int colg = colg0 + t * 16 + (lane & 15);
      const bool cv = colg < HID_;
      aov[t] = cv ? ao[colg] : 0.f;
      aod[t] = cv ? ao[HID_ + colg] : 0.f;
    }
#pragma unroll
    for (int r = 0; r < 4; ++r) {
      float sv = 0.f, dv = 0.f;
#pragma unroll
      for (int t = 0; t < 10; ++t) {
        sv = fmaf(acc[t][r], aov[t], sv);
        dv = fmaf(acc[t][r], aod[t], dv);
      }
#pragma unroll
      for (int m = 1; m <= 8; m <<= 1) {
        sv += __shfl_xor(sv, m, 64);
        dv += __shfl_xor(dv, m, 64);
      }
      if ((lane & 15) == 0) {
        s2p[(size_t)ch * 32768 + orow + r] = sv;
        d2p[(size_t)ch * 32768 + orow + r] = dv;
      }
    }
  } else {
    // Store elu + per-row-half LSE partials (acc reused to hold elu values).
    float rm[4] = {-1e30f, -1e30f, -1e30f, -1e30f};
#pragma unroll
    for (int t = 0; t < 10; ++t) {
      const int colg = colg0 + t * 16 + (lane & 15);
      const bool cv = colg < HID_;
#pragma unroll
      for (int r = 0; r < 4; ++r) {
        float ev = cv ? eluf(acc[t][r]) : -1e30f;
        if (cv) Cf[(size_t)(orow + r) * HID_ + colg] = ev;
        acc[t][r] = ev;
        rm[r] = fmaxf(rm[r], ev);
      }
    }
#pragma unroll
    for (int r = 0; r < 4; ++r) {
#pragma unroll
      for (int m = 1; m <= 8; m <<= 1)
        rm[r] = fmaxf(rm[r], __shfl_xor(rm[r], m, 64));
      float ssum = 0.f;
#pragma unroll
      for (int t = 0; t < 10; ++t) ssum += expf(acc[t][r] - rm[r]);
#pragma unroll
      for (int m = 1; m <= 8; m <<= 1) ssum += __shfl_xor(ssum, m, 64);
      if ((lane & 15) == 0) {
        s2p[(size_t)ch * 32768 + orow + r] = rm[r];   // m_half
        d2p[(size_t)ch * 32768 + orow + r] = ssum;    // sumexp_half
      }
    }
  }
}

// Merge per-half LSE partials -> mx, ls.
__global__ __launch_bounds__(256) void k7b(
    const float* __restrict__ msp, const float* __restrict__ ssp,
    float* __restrict__ mx, float* __restrict__ ls) {
  const int row = blockIdx.x * 256 + threadIdx.x;
  float m0 = msp[row], m1 = msp[32768 + row];
  float s0 = ssp[row], s1 = ssp[32768 + row];
  float m = fmaxf(m0, m1);
  float s = s0 * expf(m0 - m) + s1 * expf(m1 - m);
  mx[row] = m;
  ls[row] = logf(s);
}

// Split-K partial GEMM for small-M matmuls: grid (M/ROWS, KSPLIT).
template <int ROWS, int KSPLIT>
__global__ void gemm_skp(const float* __restrict__ A, const float* __restrict__ Bm,
                         float* __restrict__ P, int M, int K, int N) {
  const int c = threadIdx.x;
  const int r0 = blockIdx.x * ROWS;
  const int ks = blockIdx.y;
  if (c >= N) return;
  const int kchunk = (K + KSPLIT - 1) / KSPLIT;
  const int k0 = ks * kchunk;
  const int k1 = (k0 + kchunk < K) ? (k0 + kchunk) : K;
  float acc[ROWS];
#pragma unroll
  for (int r = 0; r < ROWS; ++r) acc[r] = 0.f;
  int k = k0;
  for (; k + 3 < k1; k += 4) {
    const float b0 = Bm[(size_t)(k + 0) * N + c];
    const float b1 = Bm[(size_t)(k + 1) * N + c];
    const float b2 = Bm[(size_t)(k + 2) * N + c];
    const float b3 = Bm[(size_t)(k + 3) * N + c];
#pragma unroll
    for (int r = 0; r < ROWS; ++r) {
      float4 a = ld4u(A + (size_t)(r0 + r) * K + k);
      acc[r] = fmaf(a.x, b0, acc[r]);
      acc[r] = fmaf(a.y, b1, acc[r]);
      acc[r] = fmaf(a.z, b2, acc[r]);
      acc[r] = fmaf(a.w, b3, acc[r]);
    }
  }
  for (; k < k1; ++k) {
    const float bv = Bm[(size_t)k * N + c];
#pragma unroll
    for (int r = 0; r < ROWS; ++r)
      acc[r] = fmaf(A[(size_t)(r0 + r) * K + k], bv, acc[r]);
  }
#pragma unroll
  for (int r = 0; r < ROWS; ++r)
    P[((size_t)ks * M + r0 + r) * N + c] = acc[r];
}

// Reduce split-K partials + bias + act. act: 0 none, 1 relu.
template <int KSPLIT>
__global__ void k_red(const float* __restrict__ P, const float* __restrict__ bias,
                      float* __restrict__ C, int M, int N, int ldc, int act) {
  const int idx = blockIdx.x * 256 + threadIdx.x;
  if (idx >= M * N) return;
  const int m = idx / N, c = idx - m * N;
  float v = 0.f;
#pragma unroll
  for (int p = 0; p < KSPLIT; ++p) v += P[(size_t)p * M * N + idx];
  if (bias) v += bias[c];
  if (act == 1) v = fmaxf(v, 0.f);
  C[(size_t)m * ldc + c] = v;
}

// K5: attn2 probabilities p2 (split-bf16 pair); mask-based; sums s2/d2 halves.
__global__ __launch_bounds__(256) void k5_p2(
    const float* __restrict__ s2p, const float* __restrict__ d2p,
    const unsigned long long* __restrict__ maskb, __bf16* __restrict__ p2h,
    __bf16* __restrict__ p2l) {
  const int lane = threadIdx.x & 63;
  const int row = blockIdx.x * 4 + (threadIdx.x >> 6);  // b*N+i
  const int b = row >> 7;
  float sv = s2p[row] + s2p[32768 + row];
  const float* d0 = d2p + (size_t)b * N_;
  const float* d1 = d2p + 32768 + (size_t)b * N_;
  const unsigned long long m0 = maskb[(size_t)row * 2];
  const unsigned long long m1 = maskb[(size_t)row * 2 + 1];
  float dv0 = d0[lane] + d1[lane];
  float dv1 = d0[64 + lane] + d1[64 + lane];
  float e0 = ((m0 >> lane) & 1ull) ? lrelu(sv + dv0) : NEG_;
  float e1 = ((m1 >> lane) & 1ull) ? lrelu(sv + dv1) : NEG_;
  float mx = wred_max(fmaxf(e0, e1));
  float x0 = expf(e0 - mx), x1 = expf(e1 - mx);
  float inv = 1.f / wred_sum(x0 + x1);
  float p0 = x0 * inv, p1 = x1 * inv;
  __bf16 h0 = (__bf16)p0, h1 = (__bf16)p1;
  p2h[(size_t)row * N_ + lane] = h0;
  p2l[(size_t)row * N_ + lane] = (__bf16)(p0 - (float)h0);
  p2h[(size_t)row * N_ + 64 + lane] = h1;
  p2l[(size_t)row * N_ + 64 + lane] = (__bf16)(p1 - (float)h1);
}

// K8: gat_out[b,c] = mean_i (ob[b,i,c] - mx - ls). grid 256, block 320.
__global__ void k8_mean(const float* __restrict__ ob, const float* __restrict__ mx,
                        const float* __restrict__ ls, float* __restrict__ gat) {
  const int c = threadIdx.x;
  const int b = blockIdx.x;
  if (c >= HID_) return;
  float acc = 0.f;
  for (int i = 0; i < N_; ++i) {
    int row = b * N_ + i;
    acc += ob[(size_t)row * HID_ + c] - mx[row] - ls[row];
  }
  gat[(size_t)b * HID_ + c] = acc * (1.f / N_);
}

// out[b] = sigmoid(y[b,:] @ ffn_w2 + b2). One wave per row.
__global__ __launch_bounds__(256) void k_final(
    const float* __restrict__ y, const float* __restrict__ w2,
    const float* __restrict__ b2, float* __restrict__ out) {
  const int lane = threadIdx.x & 63;
  const int b = blockIdx.x * 4 + (threadIdx.x >> 6);
  float acc = 0.f;
  for (int c = lane; c < HID_; c += 64)
    acc = fmaf(y[(size_t)b * HID_ + c], w2[c], acc);
  acc = wred_sum(acc);
  if (lane == 0) out[b] = 1.f / (1.f + expf(-(acc + b2[0])));
}

extern "C" void kernel_launch(void* const* d_in, const int* in_sizes, int n_in,
                              void* d_out, int out_size, void* d_ws, size_t ws_size,
                              hipStream_t stream) {
  const float* atom  = (const float*)d_in[0];
  const float* fp    = (const float*)d_in[1];
  const float* Whead = (const float*)d_in[2];
  const float* ah    = (const float*)d_in[3];
  const float* Wout  = (const float*)d_in[4];
  const float* aout  = (const float*)d_in[5];
  const float* fc1w  = (const float*)d_in[6];
  const float* fc1b  = (const float*)d_in[7];
  const float* fc2w  = (const float*)d_in[8];
  const float* fc2b  = (const float*)d_in[9];
  const float* fgw   = (const float*)d_in[10];
  const float* fgb   = (const float*)d_in[11];
  const float* ffw   = (const float*)d_in[12];
  const float* ffb   = (const float*)d_in[13];
  const float* w1    = (const float*)d_in[14];
  const float* b1    = (const float*)d_in[15];
  const float* w2    = (const float*)d_in[16];
  const float* b2    = (const float*)d_in[17];
  const int*   adj   = (const int*)d_in[18];
  float* out = (float*)d_out;

  float* ws = (float*)d_ws;
  // Aliased layout (peak ~138.6 MB):
  float* Wh     = ws;                      // 16,777,216 f [k1 w, k2 r]
  __bf16* Wh2Th = (__bf16*)ws;             // 9.83M u16  [gemm512 w, gemm128 r]
  __bf16* Wh2Tl = (__bf16*)(ws + 4915200);
  float* pbuf   = ws;                      // [FPN + head phases only]
  __bf16* p2h   = (__bf16*)(ws + 9830400); // 4.19M u16 each
  __bf16* p2l   = (__bf16*)(ws + 11927552);
  float* s2p    = ws + 14024704;           // [2][32768]; reused as LSE m_half
  float* d2p    = ws + 14090240;           // [2][32768]; reused as sumexp_half
  unsigned long long* maskb =
      (unsigned long long*)(ws + 14155776); // 512 KB, verified free gap
  float* sb     = ws + 16777216;
  float* db     = ws + 17039360;
  __bf16* hbh   = (__bf16*)(ws + 17301504); // 16.7M u16 each
  __bf16* hbl   = (__bf16*)(ws + 25690112);
  float* ob     = ws + 17301504;           // [gemm128 w; hb pair dead]
  float* mxb    = ws + 34078720 + 65536;
  float* lsb    = mxb + 32768;
  float* gat    = lsb + 32768;             //  76,800
  float* fpn1   = gat + 76800;             // 131,072
  float* fpn2   = fpn1 + 131072;           //  76,800
  float* xcat   = fpn2 + 76800;            // 153,600
  float* yb     = xcat + 153600;           //  76,800
  __bf16* WoutTh = (__bf16*)xcat;          // WoutT pair borrows xcat slot
  __bf16* WoutTl = (__bf16*)(xcat + 76800);//  (dead before head phase)

  // Precompute: Wout split pair; adj bitmask (k5 only).
  k_wsplit<<<600, 256, 0, stream>>>(Wout, WoutTh, WoutTl, FP2_, HID_);
  k_amask<<<8192, 256, 0, stream>>>(adj, maskb);

  // FPN branch (pbuf aliases Wh region; runs before k1)
  gemm_skp<4, 8><<<dim3(64, 8), 512, 0, stream>>>(fp, fc1w, pbuf, B_, FPD_, FP2_);
  k_red<8><<<512, 256, 0, stream>>>(pbuf, fc1b, fpn1, B_, FP2_, FP2_, 1);
  gemm_skp<4, 4><<<dim3(64, 4), 320, 0, stream>>>(fpn1, fc2w, pbuf, B_, FP2_, HID_);
  k_red<4><<<300, 256, 0, stream>>>(pbuf, fc2b, fpn2, B_, HID_, HID_, 0);

  // GAT stage 1
  k1_mfma<<<dim3(256, 8), 512, 0, stream>>>(atom, Whead, ah, Wh, sb, db);
  k2_attn1<<<2048, 512, 0, stream>>>(Wh, sb, db, adj, hbh, hbl);

  // Wh2 = hb @ Wout (+fused s2/d2 partials), output transposed split pair.
  gemm_lds<512, true><<<dim3(512, 2), 256, 0, stream>>>(
      hbh, hbl, WoutTh, WoutTl, aout, Wh2Th, Wh2Tl, s2p, d2p, nullptr);

  // GAT stage 2
  k5_p2<<<8192, 256, 0, stream>>>(s2p, d2p, maskb, p2h, p2l);
  // gemm128 writes ob + LSE partials into s2p/d2p (dead after k5).
  gemm_lds<128, false><<<dim3(512, 2), 256, 0, stream>>>(
      p2h, p2l, Wh2Th, Wh2Tl, nullptr, nullptr, nullptr, s2p, d2p, ob);
  k7b<<<128, 256, 0, stream>>>(s2p, d2p, mxb, lsb);
  k8_mean<<<256, 320, 0, stream>>>(ob, mxb, lsb, gat);

  // Head (low ws region dead -> pbuf reuse safe; xcat written after WoutT dead)
  gemm_skp<4, 4><<<dim3(64, 4), 320, 0, stream>>>(gat, fgw, pbuf, B_, HID_, HID_);
  k_red<4><<<300, 256, 0, stream>>>(pbuf, fgb, xcat, B_, HID_, 2 * HID_, 1);
  gemm_skp<4, 4><<<dim3(64, 4), 320, 0, stream>>>(fpn2, ffw, pbuf, B_, HID_, HID_);
  k_red<4><<<300, 256, 0, stream>>>(pbuf, ffb, xcat + 300, B_, HID_, 2 * HID_, 1);
  gemm_skp<4, 4><<<dim3(64, 4), 320, 0, stream>>>(xcat, w1, pbuf, B_, 2 * HID_, HID_);
  k_red<4><<<300, 256, 0, stream>>>(pbuf, b1, yb, B_, HID_, HID_, 1);
  k_final<<<64, 256, 0, stream>>>(yb, w2, b2, out);
}